// Round 12
// baseline (111.315 us; speedup 1.0000x reference)
//
#include <hip/hip_runtime.h>

#define BATCH  4096
#define LEN    8192
#define NB     12
#define TPB    256
#define EPT    32   // elements per thread; TPB*EPT == LEN

// shifted elu: ep(a) = elu(a)+1, input as = a*log2e (weights prescaled).
// ep = max(clamp01(exp2(as)), 1 + ln2*as)
//   clamp01(exp2(as)) == exp2(min(as,0)) for all finite as (monotone,
//   overflow->+inf->1, underflow->0). The clamp is the VOP3 clamp bit on
//   v_exp_f32 itself -- forced via inline asm (LLVM won't fold fmed3->clamp
//   without nnan). elu = 3 issue slots: exp(clamp), fma, max.
__device__ __forceinline__ float ep_f(float as) {
    const float LN2 = 0.6931471805599453f;
    float e;
    asm("v_exp_f32_e64 %0, %1 clamp" : "=v"(e) : "v"(as));
    return fmaxf(e, fmaf(as, LN2, 1.0f));
}

__global__ __launch_bounds__(TPB, 8)
void resconv1d_kernel(const float* __restrict__ x_in,
                      const float* __restrict__ w1,
                      const float* __restrict__ b1,
                      const float* __restrict__ w2,
                      const float* __restrict__ b2,
                      float* __restrict__ out)
{
    // halo exchange buffers (double-buffered -> one barrier per block-iter)
    __shared__ float s_first[2][TPB];
    __shared__ float s_last [2][TPB];

    const int t   = threadIdx.x;
    const int row = blockIdx.x;

    // ---- load this thread's 32 contiguous elements (8x float4) ----
    const float* xp = x_in + (size_t)row * LEN + (size_t)t * EPT;
    float y[EPT];   // carried representation: y = x + D (D starts at 0)
    #pragma unroll
    for (int k = 0; k < EPT / 4; ++k) {
        float4 v = reinterpret_cast<const float4*>(xp)[k];
        y[4*k+0] = v.x; y[4*k+1] = v.y; y[4*k+2] = v.z; y[4*k+3] = v.w;
    }

    // loop-invariant halo indices / edge flags
    const int  idxl = (t > 0)       ? t - 1 : 0;
    const int  idxr = (t < TPB - 1) ? t + 1 : TPB - 1;
    const bool at_l = (t == 0);
    const bool at_r = (t == TPB - 1);

    float D = 0.0f;   // y = x + D; updated uniformly each iteration

    #pragma unroll 1
    for (int it = 0; it < NB; ++it) {
        const int buf = it & 1;
        s_first[buf][t] = y[0];
        s_last [buf][t] = y[EPT-1];
        __syncthreads();

        // ---- uniform weight loads (loop-uniform -> scalar) ----
        const float LOG2E = 1.4426950408889634f;
        const float w10s = w1[2*it]   * LOG2E;
        const float w11s = w1[2*it+1] * LOG2E;
        const float aw20 = 0.9f * w2[2*it];
        const float aw21 = 0.9f * w2[2*it+1];
        const float cc   = 0.9f * b2[it] - aw20 - aw21;
        // fold the carried offset into the conv1 bias:
        // as = w10s*y_l + w11s*y_c + (b1*log2e - D*(w10s+w11s))
        const float b1p  = fmaf(-D, w10s + w11s, b1[it] * LOG2E);

        // halo in y-representation; row edge x==0 corresponds to y==D
        const float yl = at_l ? D : s_last [buf][idxl];
        const float yr = at_r ? D : s_first[buf][idxr];

        float as0 = fmaf(w10s, yl, fmaf(w11s, y[0], b1p));
        float ep0 = ep_f(as0);
        #pragma unroll
        for (int j = 0; j < EPT; ++j) {
            const float yn  = (j < EPT - 1) ? y[j+1] : yr;   // static select
            const float as1 = fmaf(w10s, y[j], fmaf(w11s, yn, b1p));
            const float ep1 = ep_f(as1);
            // x_new = x + cc + aw20*ep0 + aw21*ep1   (offset carried in D)
            y[j] = fmaf(aw20, ep0, fmaf(aw21, ep1, y[j]));
            ep0 = ep1;
        }
        D -= cc;   // uniform across all threads
        // next iteration writes the other halo buffer; one barrier/iter safe
    }

    // ---- store: undo the carried offset (x = y - D_final) ----
    float* op = out + (size_t)row * LEN + (size_t)t * EPT;
    #pragma unroll
    for (int k = 0; k < EPT / 4; ++k) {
        float4 v = make_float4(y[4*k+0] - D, y[4*k+1] - D,
                               y[4*k+2] - D, y[4*k+3] - D);
        reinterpret_cast<float4*>(op)[k] = v;
    }
}

extern "C" void kernel_launch(void* const* d_in, const int* in_sizes, int n_in,
                              void* d_out, int out_size, void* d_ws, size_t ws_size,
                              hipStream_t stream) {
    const float* x  = (const float*)d_in[0];
    const float* w1 = (const float*)d_in[1];
    const float* b1 = (const float*)d_in[2];
    const float* w2 = (const float*)d_in[3];
    const float* b2 = (const float*)d_in[4];
    float* out = (float*)d_out;

    resconv1d_kernel<<<dim3(BATCH), dim3(TPB), 0, stream>>>(x, w1, b1, w2, b2, out);
}

// Round 13
// 100.534 us; speedup vs baseline: 1.1072x; 1.1072x over previous
//
#include <hip/hip_runtime.h>

#define BATCH  4096
#define LEN    8192
#define NB     12
#define TPB    256
#define EPT    32   // elements per thread; TPB*EPT == LEN

// shifted elu: ep(a) = elu(a)+1, input as = a*log2e (weights prescaled).
// ep = max(clamp01(exp2(as)), 1 + ln2*as)
//   clamp01(exp2(as)) == exp2(min(as,0)) for ALL as (monotone; +inf->1, 0->0)
//   expressed as fmed3(e,0,1): single op. (Forcing the clamp into v_exp via
//   inline asm was measured WORSE -- R12: asm operand copies beat the 1-op
//   saving. Keep the compiler-scheduled form.)
__device__ __forceinline__ float ep_f(float as) {
    const float LN2 = 0.6931471805599453f;
    float e = __builtin_amdgcn_exp2f(as);
    e = __builtin_amdgcn_fmed3f(e, 0.0f, 1.0f);   // clamp-to-[0,1] idiom
    return fmaxf(e, fmaf(as, LN2, 1.0f));
}

__global__ __launch_bounds__(TPB, 8)
void resconv1d_kernel(const float* __restrict__ x_in,
                      const float* __restrict__ w1,
                      const float* __restrict__ b1,
                      const float* __restrict__ w2,
                      const float* __restrict__ b2,
                      float* __restrict__ out)
{
    // halo exchange buffers (double-buffered -> one barrier per block-iter)
    __shared__ float s_first[2][TPB];
    __shared__ float s_last [2][TPB];

    const int t   = threadIdx.x;
    const int row = blockIdx.x;

    // ---- load this thread's 32 contiguous elements (8x float4) ----
    const float* xp = x_in + (size_t)row * LEN + (size_t)t * EPT;
    float y[EPT];   // carried representation: y = x + D (D starts at 0)
    #pragma unroll
    for (int k = 0; k < EPT / 4; ++k) {
        float4 v = reinterpret_cast<const float4*>(xp)[k];
        y[4*k+0] = v.x; y[4*k+1] = v.y; y[4*k+2] = v.z; y[4*k+3] = v.w;
    }

    // loop-invariant halo indices / edge flags
    const int  idxl = (t > 0)       ? t - 1 : 0;
    const int  idxr = (t < TPB - 1) ? t + 1 : TPB - 1;
    const bool at_l = (t == 0);
    const bool at_r = (t == TPB - 1);

    float D = 0.0f;   // y = x + D; updated uniformly each iteration

    #pragma unroll 1
    for (int it = 0; it < NB; ++it) {
        const int buf = it & 1;
        s_first[buf][t] = y[0];
        s_last [buf][t] = y[EPT-1];
        __syncthreads();

        // ---- uniform weight loads (it is loop-uniform -> s_load/SGPR) ----
        const float LOG2E = 1.4426950408889634f;
        const float w10s = w1[2*it]   * LOG2E;
        const float w11s = w1[2*it+1] * LOG2E;
        const float aw20 = 0.9f * w2[2*it];
        const float aw21 = 0.9f * w2[2*it+1];
        const float cc   = 0.9f * b2[it] - aw20 - aw21;
        // fold the carried offset into the conv1 bias:
        // as = w10s*y_l + w11s*y_c + (b1*log2e - D*(w10s+w11s))
        const float b1p  = fmaf(-D, w10s + w11s, b1[it] * LOG2E);

        // halo in y-representation; row edge x==0 corresponds to y==D
        const float yl = at_l ? D : s_last [buf][idxl];
        const float yr = at_r ? D : s_first[buf][idxr];

        float as0 = fmaf(w10s, yl, fmaf(w11s, y[0], b1p));
        float ep0 = ep_f(as0);
        #pragma unroll
        for (int j = 0; j < EPT; ++j) {
            const float yn  = (j < EPT - 1) ? y[j+1] : yr;   // static select
            const float as1 = fmaf(w10s, y[j], fmaf(w11s, yn, b1p));
            const float ep1 = ep_f(as1);
            // x_new = x + cc + aw20*ep0 + aw21*ep1   (offset carried in D)
            y[j] = fmaf(aw20, ep0, fmaf(aw21, ep1, y[j]));
            ep0 = ep1;
        }
        D -= cc;   // uniform across all threads
        // next iteration writes the other halo buffer; one barrier/iter safe
    }

    // ---- store: undo the carried offset (x = y - D_final) ----
    float* op = out + (size_t)row * LEN + (size_t)t * EPT;
    #pragma unroll
    for (int k = 0; k < EPT / 4; ++k) {
        float4 v = make_float4(y[4*k+0] - D, y[4*k+1] - D,
                               y[4*k+2] - D, y[4*k+3] - D);
        reinterpret_cast<float4*>(op)[k] = v;
    }
}

extern "C" void kernel_launch(void* const* d_in, const int* in_sizes, int n_in,
                              void* d_out, int out_size, void* d_ws, size_t ws_size,
                              hipStream_t stream) {
    const float* x  = (const float*)d_in[0];
    const float* w1 = (const float*)d_in[1];
    const float* b1 = (const float*)d_in[2];
    const float* w2 = (const float*)d_in[3];
    const float* b2 = (const float*)d_in[4];
    float* out = (float*)d_out;

    resconv1d_kernel<<<dim3(BATCH), dim3(TPB), 0, stream>>>(x, w1, b1, w2, b2, out);
}